// Round 15
// baseline (782.051 us; speedup 1.0000x reference)
//
#include <hip/hip_runtime.h>
#include <math.h>

#define NGRAPH 512
#define FEATS 288   // (8+1)*32
#define EPS 1e-5f
#define NBAND 4     // src-band count for L2-resident gather (conv sweep)
#define MAXBUCK 32  // bucket arrays sized for up to 32 (runtime nbuck = 25)
#define BREP 4      // replicated global counters per bucket
#define BSHIFT 13   // bucket node range 8192 = 1<<13
#define SUBR 1024   // nodes per scatter/hist subrange block
#define IMGCAP 20480 // LDS adj image capacity (entries); expected max ~17k

typedef __attribute__((ext_vector_type(8))) short short8v;
typedef __attribute__((ext_vector_type(8))) unsigned short ushort8v;
typedef __attribute__((ext_vector_type(4))) unsigned short ushort4v;
typedef __attribute__((ext_vector_type(4))) float float4v;

// f32 -> bf16 round-to-nearest-even
__device__ __forceinline__ unsigned short f2bf(float f) {
  unsigned int u = __float_as_uint(f);
  u += 0x7fff + ((u >> 16) & 1);
  return (unsigned short)(u >> 16);
}
__device__ __forceinline__ float bf2f(unsigned short u) {
  return __uint_as_float(((unsigned int)u) << 16);
}

// exact src-band: 3 compares (no div)
__device__ __forceinline__ int srcband(int s, int bandsz) {
  return (s >= bandsz) + (s >= 2 * bandsz) + (s >= 3 * bandsz);
}

// order-preserving float atomic max (works for mixed signs, init -inf)
__device__ __forceinline__ void atomicMaxF(float* addr, float v) {
  if (v >= 0.f) atomicMax((int*)addr, __float_as_int(v));
  else atomicMin((unsigned int*)addr, __float_as_uint(v));
}

// zero/init everything once per call; first 8 blocks also convert weights
// to MFMA fragment order (absorbs the old k_prep launch).
__global__ void k_init(float* __restrict__ pooled, float* __restrict__ counts,
                       float* __restrict__ stats, int* __restrict__ degseg,
                       int* __restrict__ typemask, unsigned int* __restrict__ curpk,
                       int* __restrict__ bucketcnt, int* __restrict__ subcnt,
                       const float* __restrict__ Wh, const float* __restrict__ Wo,
                       unsigned short* __restrict__ whb, unsigned short* __restrict__ wob,
                       int N4, int N, int nsub) {
  int i = blockIdx.x * blockDim.x + threadIdx.x;
  if (i < NGRAPH * FEATS) pooled[i] = -INFINITY;
  if (i < NGRAPH) { counts[i] = 0.f; typemask[i] = 0; }
  if (i < NGRAPH * 128) stats[i] = 0.f;       // both buffers
  if (i < N4) degseg[i] = 0;
  if (i < N) curpk[i] = 0u;                   // fallback cursors
  if (i < BREP * MAXBUCK) bucketcnt[i] = 0;
  if (i < nsub) subcnt[i] = 0;

  if (blockIdx.x < 8) {
    int conv = blockIdx.x;
    const float* wh = Wh + (size_t)conv * 2048;
    const float* wo = Wo + (size_t)conv * 2048;
    unsigned short* oh = whb + (size_t)conv * 2048;
    unsigned short* oo = wob + (size_t)conv * 2048;
    for (int p = threadIdx.x; p < 2048; p += blockDim.x) {
      int rem = p & 511, l = rem >> 3, ii = rem & 7;
      int nt = p >> 9;
      int k = (l >> 4) * 8 + ii;
      int n = nt * 16 + (l & 15);
      oh[p] = f2bf(wh[k * 64 + n]);          // Wh is [32][64]
      int blk = p >> 9, nt2 = blk >> 1, ks = blk & 1;
      int k2 = ks * 32 + (l >> 4) * 8 + ii;
      int n2 = nt2 * 16 + (l & 15);
      oo[p] = f2bf(wo[k2 * 32 + n2]);        // Wo is [64][32]
    }
  }
}

// 8 threads/node: thread q writes channels 4q..4q+3 of hbf (bf16 only).
__global__ __launch_bounds__(256) void k_embed(
    const int* __restrict__ x, const int* __restrict__ batch,
    const float* __restrict__ emb, unsigned short* __restrict__ hbf,
    int* __restrict__ typemask, float* __restrict__ counts, int N) {
  long t = (long)blockIdx.x * blockDim.x + threadIdx.x;
  int n = (int)(t >> 3), q = (int)(t & 7);
  int lane = threadIdx.x & 63;
  bool valid = (n < N);
  int g = 0, tt = 0;
  if (valid) {
    g = batch[n];
    tt = x[n];
    float4 e = *((const float4*)(emb + (size_t)tt * 32 + q * 4));
    ushort4v hb;
    hb[0] = f2bf(e.x); hb[1] = f2bf(e.y); hb[2] = f2bf(e.z); hb[3] = f2bf(e.w);
    *((ushort4v*)(hbf + (size_t)n * 32 + q * 4)) = hb;
  }
  int g0 = __shfl(g, 0);
  bool uniform = __all(valid) && __all(g == g0);
  int m = valid ? (1 << tt) : 0;
  if (uniform) {
    #pragma unroll
    for (int d = 1; d < 64; d <<= 1) m |= __shfl_xor(m, d);
    if (lane == 0) {
      atomicOr(&typemask[g0], m);
      atomicAdd(&counts[g0], 8.f);   // 64 lanes = 8 nodes
    }
  } else if (valid && q == 0) {
    atomicOr(&typemask[g], m);
    atomicAdd(&counts[g], 1.f);
  }
}

// pooled[g][0:32] = max over types present in g of emb[t][:]
__global__ void k_pool0(const int* __restrict__ typemask, const float* __restrict__ emb,
                        float* __restrict__ pooled) {
  int i = blockIdx.x * blockDim.x + threadIdx.x;
  if (i >= NGRAPH * 32) return;
  int g = i >> 5, c = i & 31;
  int m = typemask[g];
  float v = -INFINITY;
  #pragma unroll
  for (int t = 0; t < 6; t++)
    if (m & (1 << t)) v = fmaxf(v, emb[t * 32 + c]);
  pooled[(size_t)g * FEATS + c] = v;
}

// ---------------- CSR build v3: two-level bin + LDS assembly ----------
__global__ __launch_bounds__(256) void k_bin(
    const int* __restrict__ src, const int* __restrict__ dst, int E,
    int cap4, int* __restrict__ bucketcnt, unsigned int* __restrict__ ebuf,
    int bandsz) {
  __shared__ int lcnt[MAXBUCK];
  __shared__ int gbase[MAXBUCK];
  for (int i = threadIdx.x; i < MAXBUCK; i += 256) lcnt[i] = 0;
  __syncthreads();
  int e0 = blockIdx.x * 2048 + threadIdx.x;
  int bArr[8], rArr[8];
  unsigned int pArr[8];
  #pragma unroll
  for (int it = 0; it < 8; it++) {
    int e = e0 + it * 256;
    bArr[it] = -1;
    if (e < E) {
      int d = dst[e];
      int s = src[e];
      int b = d >> BSHIFT;
      int sb = srcband(s, bandsz);
      pArr[it] = ((unsigned int)(d & ((1 << BSHIFT) - 1)) << 18)
               | ((unsigned int)sb << 16) | (unsigned int)(s - sb * bandsz);
      rArr[it] = atomicAdd(&lcnt[b], 1);
      bArr[it] = b;
    }
  }
  __syncthreads();
  int rep = blockIdx.x & (BREP - 1);
  if (threadIdx.x < MAXBUCK) {
    int b = threadIdx.x;
    int c = lcnt[b];
    gbase[b] = (c > 0) ? atomicAdd(&bucketcnt[rep * MAXBUCK + b], c) : 0;
  }
  __syncthreads();
  #pragma unroll
  for (int it = 0; it < 8; it++) {
    if (bArr[it] >= 0) {
      int b = bArr[it];
      int pos = gbase[b] + rArr[it];
      if (pos < cap4)
        ebuf[((size_t)b * BREP + rep) * cap4 + pos] = pArr[it];
    }
  }
}

// re-partition (bucket,rep) list into 8 per-subrange lists.
__global__ __launch_bounds__(1024) void k_bin2(
    const unsigned int* __restrict__ ebuf, const int* __restrict__ bucketcnt,
    int cap4, int* __restrict__ subcnt, unsigned int* __restrict__ ebuf2,
    int cap2) {
  __shared__ int lcnt[8];
  __shared__ int gbase[8];
  int p = blockIdx.x >> 2;
  int rep = blockIdx.x & 3;
  int cnt = min(bucketcnt[rep * MAXBUCK + p], cap4);
  const unsigned int* base = ebuf + ((size_t)p * BREP + rep) * cap4;
  for (int c0 = 0; c0 < cnt; c0 += 1024) {
    if (threadIdx.x < 8) lcnt[threadIdx.x] = 0;
    __syncthreads();
    int idx = c0 + threadIdx.x;
    int j = -1, rank = 0;
    unsigned int pk = 0;
    if (idx < cnt) {
      pk = base[idx];
      j = (int)((pk >> 28) & 7u);
      rank = atomicAdd(&lcnt[j], 1);
    }
    __syncthreads();
    if (threadIdx.x < 8) {
      int c = lcnt[threadIdx.x];
      gbase[threadIdx.x] = (c > 0) ? atomicAdd(&subcnt[p * 8 + threadIdx.x], c) : 0;
    }
    __syncthreads();
    if (j >= 0) {
      int pos = gbase[j] + rank;
      if (pos < cap2)
        ebuf2[(size_t)(p * 8 + j) * cap2 + pos] = pk;
    }
    __syncthreads();
  }
}

// exact per-segment counts -> degseg (no global atomics, 1x scan)
__global__ __launch_bounds__(1024) void k_histL2(
    const unsigned int* __restrict__ ebuf2, const int* __restrict__ subcnt,
    int cap2, int* __restrict__ degseg, int N) {
  __shared__ unsigned int cpk[SUBR];
  int s = blockIdx.x;
  int node0 = s << 10;
  if (node0 >= N) return;
  int nEnd = min(node0 + SUBR, N);
  for (int i = threadIdx.x; i < SUBR; i += 1024) cpk[i] = 0u;
  __syncthreads();
  int cnt = min(subcnt[s], cap2);
  const unsigned int* base = ebuf2 + (size_t)s * cap2;
  for (int idx = threadIdx.x; idx < cnt; idx += 1024) {
    unsigned int pk = base[idx];
    int local = (int)((pk >> 18) & 1023u);
    int sb = (int)((pk >> 16) & 3u);
    atomicAdd(&cpk[local], 1u << (sb * 8));
  }
  __syncthreads();
  for (int i = threadIdx.x; i < nEnd - node0; i += 1024) {
    unsigned int v = cpk[i];
    int* dp = degseg + (size_t)(node0 + i) * 4;
    dp[0] = (int)(v & 0xffu);
    dp[1] = (int)((v >> 8) & 0xffu);
    dp[2] = (int)((v >> 16) & 0xffu);
    dp[3] = (int)(v >> 24);
  }
}

// assemble subrange adj image in LDS, stream to global coalesced (1x scan)
__global__ __launch_bounds__(1024) void k_scatL2(
    const unsigned int* __restrict__ ebuf2, const int* __restrict__ subcnt,
    int cap2, const int* __restrict__ rowseg, unsigned int* __restrict__ curpk,
    unsigned short* __restrict__ adj, int E, int N) {
  __shared__ unsigned short img[IMGCAP];
  __shared__ unsigned int cpk[SUBR];
  int s = blockIdx.x;
  int node0 = s << 10;
  if (node0 >= N) return;
  int nEnd = min(node0 + SUBR, N);
  int imgbase = rowseg[(size_t)node0 * 4];
  int imgend = (nEnd < N) ? rowseg[(size_t)nEnd * 4] : E;
  int isz = imgend - imgbase;
  bool lds = (isz <= IMGCAP);
  for (int i = threadIdx.x; i < SUBR; i += 1024) cpk[i] = 0u;
  __syncthreads();
  int cnt = min(subcnt[s], cap2);
  const unsigned int* base = ebuf2 + (size_t)s * cap2;
  for (int idx = threadIdx.x; idx < cnt; idx += 1024) {
    unsigned int pk = base[idx];
    int local = (int)((pk >> 18) & 1023u);
    int sb = (int)((pk >> 16) & 3u);
    int node = node0 + local;
    int seg = node * 4 + sb;
    unsigned short srel = (unsigned short)(pk & 0xffffu);
    if (lds) {
      unsigned int old = atomicAdd(&cpk[local], 1u << (sb * 8));
      int rank = (int)((old >> (sb * 8)) & 0xffu);
      img[rowseg[seg] + rank - imgbase] = srel;
    } else {
      unsigned int old = atomicAdd(&curpk[seg >> 2], 1u << ((seg & 3) * 8));
      int rank = (int)((old >> ((seg & 3) * 8)) & 0xffu);
      adj[rowseg[seg] + rank] = srel;
    }
  }
  __syncthreads();
  if (lds) {
    for (int i = threadIdx.x; i < isz; i += 1024)
      adj[imgbase + i] = img[i];
  }
}

// ---- fallback (r12) hist/scatter, used only if ws too small ----
__global__ void k_hist(const int* __restrict__ dst, const int* __restrict__ src,
                       int* __restrict__ degseg, int E, int eb,
                       int dband, int bandsz, int N) {
  int band = blockIdx.x / eb;
  int e = (blockIdx.x - band * eb) * blockDim.x + threadIdx.x;
  if (e >= E) return;
  int bandlo = band * dband;
  int bandhi = min(bandlo + dband, N);
  int d = dst[e];
  if (d < bandlo || d >= bandhi) return;
  int sb = srcband(src[e], bandsz);
  atomicAdd(&degseg[(size_t)d * 4 + sb], 1);
}

__global__ void k_scatter(const int* __restrict__ src, const int* __restrict__ dst,
                          const int* __restrict__ rowseg, unsigned int* __restrict__ curpk,
                          unsigned short* __restrict__ adj, int E,
                          int eb, int dband, int bandsz, int N) {
  int band = blockIdx.x / eb;
  int e = (blockIdx.x - band * eb) * blockDim.x + threadIdx.x;
  if (e >= E) return;
  int bandlo = band * dband;
  int bandhi = min(bandlo + dband, N);
  int d = dst[e];
  if (d < bandlo || d >= bandhi) return;
  int s = src[e];
  int sb = srcband(s, bandsz);
  int seg = d * 4 + sb;
  unsigned int old = atomicAdd(&curpk[seg >> 2], 1u << ((seg & 3) * 8));
  int local = (int)((old >> ((seg & 3) * 8)) & 0xffu);
  adj[rowseg[seg] + local] = (unsigned short)(s - sb * bandsz);
}

__global__ void k_scan_block(const int* __restrict__ deg, int* __restrict__ excl,
                             int* __restrict__ bsum, int N) {
  __shared__ int s[256];
  int i = blockIdx.x * 256 + threadIdx.x;
  int t = threadIdx.x;
  int v = (i < N) ? deg[i] : 0;
  s[t] = v;
  __syncthreads();
  for (int off = 1; off < 256; off <<= 1) {
    int add = (t >= off) ? s[t - off] : 0;
    __syncthreads();
    s[t] += add;
    __syncthreads();
  }
  if (i < N) excl[i] = s[t] - v;
  if (t == 255) bsum[blockIdx.x] = s[255];
}

__global__ void k_scan_bsum(int* __restrict__ bsum, int nb) {
  __shared__ int s[256];
  __shared__ int carry;
  int t = threadIdx.x;
  if (t == 0) carry = 0;
  __syncthreads();
  for (int base = 0; base < nb; base += 256) {
    int i = base + t;
    int v = (i < nb) ? bsum[i] : 0;
    s[t] = v;
    __syncthreads();
    for (int off = 1; off < 256; off <<= 1) {
      int add = (t >= off) ? s[t - off] : 0;
      __syncthreads();
      s[t] += add;
      __syncthreads();
    }
    if (i < nb) bsum[i] = s[t] - v + carry;
    __syncthreads();
    if (t == 0) carry += s[255];
    __syncthreads();
  }
}

__global__ void k_scan_add(int* __restrict__ excl, const int* __restrict__ bsum, int N) {
  int i = blockIdx.x * 256 + threadIdx.x;
  if (i < N) excl[i] = excl[i] + bsum[blockIdx.x];
}

// ---------------- fused conv: phase-aligned band sweep + quarter-row gather --
// r14 config + BALANCED TILE ASSIGNMENT (r15): wave w owns tiles
// [w*ntiles/8192, (w+1)*ntiles/8192) — exact partition, 1 or 2 ADJACENT
// tiles/wave. r14's stride-8192 split gave waves 0..4307 two tiles and the
// rest one; blockIdx-contiguous waves -> whole CUs at 64 tiles vs 32 ->
// ~24% idle tail per dispatch. Balanced: every CU ~48.8 tiles.
// Band-outer sweep (phase-aligned L2 slices) unchanged. Segment tables
// hoisted as int4 pairs per tile.
__global__ __launch_bounds__(256, 8) void k_conv(
    const unsigned short* __restrict__ hbf,
    const unsigned short* __restrict__ adj, const int* __restrict__ rowseg,
    const int* __restrict__ degseg,
    const unsigned short* __restrict__ whb, const float* __restrict__ bh,
    const unsigned short* __restrict__ wob, const float* __restrict__ bo,
    const int* __restrict__ batch, unsigned short* __restrict__ z2,
    float* __restrict__ stats, float* __restrict__ statsOther,
    int bandsz, int N) {
  __shared__ unsigned short sWhB[4 * 64 * 8];     // [nt][lane][i]
  __shared__ unsigned short sWoB[2 * 2 * 64 * 8]; // [nt2*2+ks][lane][i]
  __shared__ unsigned short st[4][16][72];        // per-wave t buf, +8 pad

  {
    int zi = blockIdx.x * 256 + threadIdx.x;
    if (zi < NGRAPH * 64) statsOther[zi] = 0.f;
    int p = threadIdx.x * 8;
    *((ushort8v*)&sWhB[p]) = *((const ushort8v*)&whb[p]);
    *((ushort8v*)&sWoB[p]) = *((const ushort8v*)&wob[p]);
  }
  __syncthreads();

  int wid = threadIdx.x >> 6;
  int lane = threadIdx.x & 63;
  int col = lane & 15;
  int grp = lane >> 4;
  int w = blockIdx.x * 4 + wid;            // 0..8191
  int ntiles = (N + 15) >> 4;

  // balanced contiguous assignment: tiles [w*ntiles>>13, (w+1)*ntiles>>13)
  int tstart = (int)(((long)w * ntiles) >> 13);
  int tend = (int)(((long)(w + 1) * ntiles) >> 13);
  int tileArr[2];
  tileArr[0] = tstart;
  tileArr[1] = (tend - tstart > 1) ? (tstart + 1) : ntiles;   // sentinel

  const unsigned short* __restrict__ qb = hbf + grp * 8;

  // hoist per-tile segment tables (one int4 pair per tile)
  int sT[2][4], dT[2][4];
  #pragma unroll
  for (int t = 0; t < 2; t++) {
    #pragma unroll
    for (int b = 0; b < 4; b++) { sT[t][b] = 0; dT[t][b] = 0; }
    int tile = tileArr[t];
    if (tile < ntiles) {
      int node = tile * 16 + col;
      if (node < N) {
        int4 s4 = *((const int4*)(rowseg + (size_t)node * 4));
        int4 d4 = *((const int4*)(degseg + (size_t)node * 4));
        sT[t][0] = s4.x; sT[t][1] = s4.y; sT[t][2] = s4.z; sT[t][3] = s4.w;
        dT[t][0] = d4.x; dT[t][1] = d4.y; dT[t][2] = d4.z; dT[t][3] = d4.w;
      }
    }
  }

  float keepT[2][8];
  #pragma unroll
  for (int t = 0; t < 2; t++)
    #pragma unroll
    for (int i = 0; i < 8; i++) keepT[t][i] = 0.f;

  // band-major gather sweep
  #pragma unroll
  for (int b = 0; b < 4; b++) {
    const unsigned short* __restrict__ bq = qb + (size_t)(b * bandsz) * 32;
    #pragma unroll
    for (int t = 0; t < 2; t++) {
      if (tileArr[t] >= ntiles) continue;  // wave-uniform branch
      int s0 = sT[t][b], dg = dT[t][b];
      int k = 0;
      for (; k + 4 <= dg; k += 4) {
        int sA = adj[s0 + k + 0];
        int sB = adj[s0 + k + 1];
        int sC = adj[s0 + k + 2];
        int sD = adj[s0 + k + 3];
        ushort8v a = *((const ushort8v*)(bq + (size_t)sA * 32));
        ushort8v bv = *((const ushort8v*)(bq + (size_t)sB * 32));
        ushort8v c = *((const ushort8v*)(bq + (size_t)sC * 32));
        ushort8v d = *((const ushort8v*)(bq + (size_t)sD * 32));
        #pragma unroll
        for (int i = 0; i < 8; i++) {
          keepT[t][i] += bf2f(a[i]);
          keepT[t][i] += bf2f(bv[i]);
          keepT[t][i] += bf2f(c[i]);
          keepT[t][i] += bf2f(d[i]);
        }
      }
      if (k + 2 <= dg) {
        int sA = adj[s0 + k + 0];
        int sB = adj[s0 + k + 1];
        ushort8v a = *((const ushort8v*)(bq + (size_t)sA * 32));
        ushort8v bv = *((const ushort8v*)(bq + (size_t)sB * 32));
        #pragma unroll
        for (int i = 0; i < 8; i++) {
          keepT[t][i] += bf2f(a[i]);
          keepT[t][i] += bf2f(bv[i]);
        }
        k += 2;
      }
      if (k < dg) {
        int sA = adj[s0 + k];
        ushort8v a = *((const ushort8v*)(bq + (size_t)sA * 32));
        #pragma unroll
        for (int i = 0; i < 8; i++) keepT[t][i] += bf2f(a[i]);
      }
    }
  }

  // epilogue per tile: z -> MLP -> z2, stats
  #pragma unroll
  for (int t = 0; t < 2; t++) {
    int tile = tileArr[t];
    if (tile >= ntiles) continue;
    int base = tile * 16;
    int node = base + col;

    float zf[8];
    if (node < N) {
      ushort8v own = *((const ushort8v*)(hbf + (size_t)node * 32 + grp * 8));
      #pragma unroll
      for (int i = 0; i < 8; i++) zf[i] = bf2f(own[i]) + keepT[t][i];
    } else {
      #pragma unroll
      for (int i = 0; i < 8; i++) zf[i] = 0.f;
    }
    short8v afrag;
    #pragma unroll
    for (int i = 0; i < 8; i++) afrag[i] = (short)f2bf(zf[i]);

    // layer 1: t1 = relu(z @ Wh + bh) -> bf16 in per-wave LDS
    #pragma unroll
    for (int nt = 0; nt < 4; nt++) {
      float b = bh[nt * 16 + col];
      float4v acc1 = {b, b, b, b};
      short8v bfrag = *((const short8v*)&sWhB[(nt * 64 + lane) * 8]);
      acc1 = __builtin_amdgcn_mfma_f32_16x16x32_bf16(afrag, bfrag, acc1, 0, 0, 0);
      #pragma unroll
      for (int r = 0; r < 4; r++) {
        st[wid][grp * 4 + r][nt * 16 + col] = f2bf(fmaxf(acc1[r], 0.f));
      }
    }
    // same-wave LDS RAW/WAR: DS ops are in-order per wave.

    // layer 2: o = t1 @ Wo + bo
    short8v a2[2];
    #pragma unroll
    for (int ks = 0; ks < 2; ks++)
      a2[ks] = *((const short8v*)&st[wid][col][ks * 32 + grp * 8]);

    float4v acc2[2];
    #pragma unroll
    for (int nt2 = 0; nt2 < 2; nt2++) {
      float b = bo[nt2 * 16 + col];
      acc2[nt2] = (float4v){b, b, b, b};
      #pragma unroll
      for (int ks = 0; ks < 2; ks++) {
        short8v bfrag = *((const short8v*)&sWoB[((nt2 * 2 + ks) * 64 + lane) * 8]);
        acc2[nt2] = __builtin_amdgcn_mfma_f32_16x16x32_bf16(a2[ks], bfrag, acc2[nt2], 0, 0, 0);
      }
    }

    // store z2 (bf16, nt streaming store)
    #pragma unroll
    for (int nt2 = 0; nt2 < 2; nt2++) {
      #pragma unroll
      for (int r = 0; r < 4; r++) {
        int nd = base + grp * 4 + r;
        if (nd < N)
          __builtin_nontemporal_store(f2bf(acc2[nt2][r]), z2 + (size_t)nd * 32 + nt2 * 16 + col);
      }
    }

    // per-graph stats
    int g0 = batch[base];
    int gLast = batch[min(base + 15, N - 1)];
    if ((base + 16 <= N) && g0 == gLast) {
      #pragma unroll
      for (int nt2 = 0; nt2 < 2; nt2++) {
        float s = acc2[nt2][0] + acc2[nt2][1] + acc2[nt2][2] + acc2[nt2][3];
        float ss = acc2[nt2][0] * acc2[nt2][0] + acc2[nt2][1] * acc2[nt2][1]
                 + acc2[nt2][2] * acc2[nt2][2] + acc2[nt2][3] * acc2[nt2][3];
        s += __shfl_xor(s, 16); s += __shfl_xor(s, 32);
        ss += __shfl_xor(ss, 16); ss += __shfl_xor(ss, 32);
        if (grp == 0) {
          atomicAdd(&stats[(size_t)g0 * 64 + nt2 * 16 + col], s);
          atomicAdd(&stats[(size_t)g0 * 64 + 32 + nt2 * 16 + col], ss);
        }
      }
    } else {
      #pragma unroll
      for (int nt2 = 0; nt2 < 2; nt2++) {
        #pragma unroll
        for (int r = 0; r < 4; r++) {
          int nd = base + grp * 4 + r;
          if (nd < N) {
            int g = batch[nd];
            float v = acc2[nt2][r];
            atomicAdd(&stats[(size_t)g * 64 + nt2 * 16 + col], v);
            atomicAdd(&stats[(size_t)g * 64 + 32 + nt2 * 16 + col], v * v);
          }
        }
      }
    }
  }
}

// ---------------- conv 0 specialization ----------------
__global__ __launch_bounds__(256, 4) void k_conv0(
    const unsigned short* __restrict__ hbf,
    const unsigned short* __restrict__ adj, const int* __restrict__ rowseg,
    const int* __restrict__ degseg,
    const int* __restrict__ x, const float* __restrict__ emb,
    const unsigned short* __restrict__ whb, const float* __restrict__ bh,
    const unsigned short* __restrict__ wob, const float* __restrict__ bo,
    const int* __restrict__ batch, unsigned short* __restrict__ z2,
    float* __restrict__ stats, float* __restrict__ statsOther,
    int bandsz, int N) {
  __shared__ unsigned short sWhB[4 * 64 * 8];
  __shared__ unsigned short sWoB[2 * 2 * 64 * 8];
  __shared__ unsigned short st[4][16][72];
  __shared__ float sEmb[6][32];

  {
    int zi = blockIdx.x * 256 + threadIdx.x;
    if (zi < NGRAPH * 64) statsOther[zi] = 0.f;
    int p = threadIdx.x * 8;
    *((ushort8v*)&sWhB[p]) = *((const ushort8v*)&whb[p]);
    *((ushort8v*)&sWoB[p]) = *((const ushort8v*)&wob[p]);
    if (threadIdx.x < 192) ((float*)sEmb)[threadIdx.x] = emb[threadIdx.x];
  }
  __syncthreads();

  int wid = threadIdx.x >> 6;
  int lane = threadIdx.x & 63;
  int tile = blockIdx.x * 4 + wid;
  int base = tile * 16;
  if (base >= N) return;
  int col = lane & 15;
  int grp = lane >> 4;
  int node = base + col;

  int sArr[4] = {0, 0, 0, 0}, dArr[4] = {0, 0, 0, 0};
  if (node < N) {
    int4 s4 = *((const int4*)(rowseg + (size_t)node * 4));
    int4 d4 = *((const int4*)(degseg + (size_t)node * 4));
    sArr[0] = s4.x; sArr[1] = s4.y; sArr[2] = s4.z; sArr[3] = s4.w;
    dArr[0] = d4.x; dArr[1] = d4.y; dArr[2] = d4.z; dArr[3] = d4.w;
  }

  float c0 = 0.f, c1 = 0.f, c2 = 0.f, c3 = 0.f, c4 = 0.f, c5 = 0.f;
  #pragma unroll
  for (int b = 0; b < 4; b++) {
    int s0 = sArr[b], dg = dArr[b];
    int bbase = b * bandsz;
    for (int j = grp; j < dg; j += 4) {
      int sA = bbase + (int)adj[s0 + j];
      int tA = x[sA];
      c0 += (tA == 0) ? 1.f : 0.f; c1 += (tA == 1) ? 1.f : 0.f;
      c2 += (tA == 2) ? 1.f : 0.f; c3 += (tA == 3) ? 1.f : 0.f;
      c4 += (tA == 4) ? 1.f : 0.f; c5 += (tA == 5) ? 1.f : 0.f;
    }
  }

  c0 += __shfl_xor(c0, 16); c0 += __shfl_xor(c0, 32);
  c1 += __shfl_xor(c1, 16); c1 += __shfl_xor(c1, 32);
  c2 += __shfl_xor(c2, 16); c2 += __shfl_xor(c2, 32);
  c3 += __shfl_xor(c3, 16); c3 += __shfl_xor(c3, 32);
  c4 += __shfl_xor(c4, 16); c4 += __shfl_xor(c4, 32);
  c5 += __shfl_xor(c5, 16); c5 += __shfl_xor(c5, 32);

  float zf[8];
  if (node < N) {
    ushort8v own = *((const ushort8v*)(hbf + (size_t)node * 32 + grp * 8));
    #pragma unroll
    for (int i = 0; i < 8; i++) {
      int ch = grp * 8 + i;
      float v = bf2f(own[i]);
      v = fmaf(c0, sEmb[0][ch], v);
      v = fmaf(c1, sEmb[1][ch], v);
      v = fmaf(c2, sEmb[2][ch], v);
      v = fmaf(c3, sEmb[3][ch], v);
      v = fmaf(c4, sEmb[4][ch], v);
      v = fmaf(c5, sEmb[5][ch], v);
      zf[i] = v;
    }
  } else {
    #pragma unroll
    for (int i = 0; i < 8; i++) zf[i] = 0.f;
  }
  short8v afrag;
  #pragma unroll
  for (int i = 0; i < 8; i++) afrag[i] = (short)f2bf(zf[i]);

  #pragma unroll
  for (int nt = 0; nt < 4; nt++) {
    float b = bh[nt * 16 + col];
    float4v acc1 = {b, b, b, b};
    short8v bfrag = *((const short8v*)&sWhB[(nt * 64 + lane) * 8]);
    acc1 = __builtin_amdgcn_mfma_f32_16x16x32_bf16(afrag, bfrag, acc1, 0, 0, 0);
    #pragma unroll
    for (int r = 0; r < 4; r++) {
      st[wid][grp * 4 + r][nt * 16 + col] = f2bf(fmaxf(acc1[r], 0.f));
    }
  }

  short8v a2[2];
  #pragma unroll
  for (int ks = 0; ks < 2; ks++)
    a2[ks] = *((const short8v*)&st[wid][col][ks * 32 + grp * 8]);

  float4v acc2[2];
  #pragma unroll
  for (int nt2 = 0; nt2 < 2; nt2++) {
    float b = bo[nt2 * 16 + col];
    acc2[nt2] = (float4v){b, b, b, b};
    #pragma unroll
    for (int ks = 0; ks < 2; ks++) {
      short8v bfrag = *((const short8v*)&sWoB[((nt2 * 2 + ks) * 64 + lane) * 8]);
      acc2[nt2] = __builtin_amdgcn_mfma_f32_16x16x32_bf16(a2[ks], bfrag, acc2[nt2], 0, 0, 0);
    }
  }

  #pragma unroll
  for (int nt2 = 0; nt2 < 2; nt2++) {
    #pragma unroll
    for (int r = 0; r < 4; r++) {
      int nd = base + grp * 4 + r;
      if (nd < N)
        __builtin_nontemporal_store(f2bf(acc2[nt2][r]), z2 + (size_t)nd * 32 + nt2 * 16 + col);
    }
  }

  int g0 = batch[base];
  int gLast = batch[min(base + 15, N - 1)];
  if ((base + 16 <= N) && g0 == gLast) {
    #pragma unroll
    for (int nt2 = 0; nt2 < 2; nt2++) {
      float s = acc2[nt2][0] + acc2[nt2][1] + acc2[nt2][2] + acc2[nt2][3];
      float ss = acc2[nt2][0] * acc2[nt2][0] + acc2[nt2][1] * acc2[nt2][1]
               + acc2[nt2][2] * acc2[nt2][2] + acc2[nt2][3] * acc2[nt2][3];
      s += __shfl_xor(s, 16); s += __shfl_xor(s, 32);
      ss += __shfl_xor(ss, 16); ss += __shfl_xor(ss, 32);
      if (grp == 0) {
        atomicAdd(&stats[(size_t)g0 * 64 + nt2 * 16 + col], s);
        atomicAdd(&stats[(size_t)g0 * 64 + 32 + nt2 * 16 + col], ss);
      }
    }
  } else {
    #pragma unroll
    for (int nt2 = 0; nt2 < 2; nt2++) {
      #pragma unroll
      for (int r = 0; r < 4; r++) {
        int nd = base + grp * 4 + r;
        if (nd < N) {
          int g = batch[nd];
          float v = acc2[nt2][r];
          atomicAdd(&stats[(size_t)g * 64 + nt2 * 16 + col], v);
          atomicAdd(&stats[(size_t)g * 64 + 32 + nt2 * 16 + col], v * v);
        }
      }
    }
  }
}

// h = relu(h + (z2-mean)*inv) with h kept in bf16 (hbf). 8 threads/node.
__global__ __launch_bounds__(256) void k_norm(
    unsigned short* __restrict__ hbf, const unsigned short* __restrict__ z2,
    const float* __restrict__ stats, const float* __restrict__ counts,
    const int* __restrict__ batch, float* __restrict__ pooled, int conv, int N) {
  long t = (long)blockIdx.x * blockDim.x + threadIdx.x;
  int n = (int)(t >> 3), q = (int)(t & 7);
  int lane = threadIdx.x & 63;
  bool valid = (n < N);

  int g = 0;
  float r0 = -INFINITY, r1 = -INFINITY, r2 = -INFINITY, r3 = -INFINITY;
  if (valid) {
    g = batch[n];
    float cnt = counts[g];
    float4 sv = *((const float4*)(stats + (size_t)g * 64 + q * 4));
    float4 qv = *((const float4*)(stats + (size_t)g * 64 + 32 + q * 4));
    float m0 = 0.f, m1 = 0.f, m2 = 0.f, m3 = 0.f;
    float i0 = 0.f, i1 = 0.f, i2 = 0.f, i3 = 0.f;
    if (cnt > 0.f) {
      m0 = sv.x / cnt; m1 = sv.y / cnt; m2 = sv.z / cnt; m3 = sv.w / cnt;
      i0 = rsqrtf(fmaxf(qv.x / cnt - m0 * m0, 0.f) + EPS);
      i1 = rsqrtf(fmaxf(qv.y / cnt - m1 * m1, 0.f) + EPS);
      i2 = rsqrtf(fmaxf(qv.z / cnt - m2 * m2, 0.f) + EPS);
      i3 = rsqrtf(fmaxf(qv.w / cnt - m3 * m3, 0.f) + EPS);
    }
    ushort4v hb = *((const ushort4v*)(hbf + (size_t)n * 32 + q * 4));
    ushort4v zv = *((const ushort4v*)(z2 + (size_t)n * 32 + q * 4));
    r0 = fmaxf(bf2f(hb[0]) + (bf2f(zv[0]) - m0) * i0, 0.f);
    r1 = fmaxf(bf2f(hb[1]) + (bf2f(zv[1]) - m1) * i1, 0.f);
    r2 = fmaxf(bf2f(hb[2]) + (bf2f(zv[2]) - m2) * i2, 0.f);
    r3 = fmaxf(bf2f(hb[3]) + (bf2f(zv[3]) - m3) * i3, 0.f);
    hb[0] = f2bf(r0); hb[1] = f2bf(r1); hb[2] = f2bf(r2); hb[3] = f2bf(r3);
    *((ushort4v*)(hbf + (size_t)n * 32 + q * 4)) = hb;
  }

  int g0 = __shfl(g, 0);
  bool uniform = __all(valid) && __all(g == g0);
  if (uniform) {
    float m0 = r0, m1 = r1, m2 = r2, m3 = r3;
    #pragma unroll
    for (int d = 8; d < 64; d <<= 1) {
      m0 = fmaxf(m0, __shfl_xor(m0, d));
      m1 = fmaxf(m1, __shfl_xor(m1, d));
      m2 = fmaxf(m2, __shfl_xor(m2, d));
      m3 = fmaxf(m3, __shfl_xor(m3, d));
    }
    if (lane < 8) {
      float* poolrow = pooled + (size_t)g0 * FEATS + (conv + 1) * 32 + lane * 4;
      atomicMaxF(poolrow + 0, m0);
      atomicMaxF(poolrow + 1, m1);
      atomicMaxF(poolrow + 2, m2);
      atomicMaxF(poolrow + 3, m3);
    }
  } else if (valid) {
    float* poolrow = pooled + (size_t)g * FEATS + (conv + 1) * 32 + q * 4;
    atomicMaxF(poolrow + 0, r0);
    atomicMaxF(poolrow + 1, r1);
    atomicMaxF(poolrow + 2, r2);
    atomicMaxF(poolrow + 3, r3);
  }
}

// hid = relu(pooled @ W_hid + b_hid); out = hid @ W_out + b_out
__global__ __launch_bounds__(64) void k_head(
    const float* __restrict__ pooled, const float* __restrict__ W_hid,
    const float* __restrict__ b_hid, const float* __restrict__ W_out,
    const float* __restrict__ b_out, float* __restrict__ out) {
  __shared__ float sp[FEATS];
  __shared__ float sh[64];
  int g = blockIdx.x;
  for (int i = threadIdx.x; i < FEATS; i += 64) sp[i] = pooled[(size_t)g * FEATS + i];
  __syncthreads();
  int j = threadIdx.x;
  float acc = b_hid[j];
  for (int k = 0; k < FEATS; k++) acc = fmaf(sp[k], W_hid[k * 64 + j], acc);
  sh[j] = fmaxf(acc, 0.f);
  __syncthreads();
  if (j < 32) {
    float o = b_out[j];
    #pragma unroll
    for (int k = 0; k < 64; k++) o = fmaf(sh[k], W_out[k * 32 + j], o);
    out[(size_t)g * 32 + j] = o;
  }
}

extern "C" void kernel_launch(void* const* d_in, const int* in_sizes, int n_in,
                              void* d_out, int out_size, void* d_ws, size_t ws_size,
                              hipStream_t stream) {
  const int* x      = (const int*)d_in[0];
  const int* edge   = (const int*)d_in[1];
  const int* batch  = (const int*)d_in[2];
  const float* emb  = (const float*)d_in[3];
  const float* Wh   = (const float*)d_in[4];
  const float* bh   = (const float*)d_in[5];
  const float* Wo   = (const float*)d_in[6];
  const float* bo   = (const float*)d_in[7];
  const float* W_hid = (const float*)d_in[8];
  const float* b_hid = (const float*)d_in[9];
  const float* W_out = (const float*)d_in[10];
  const float* b_out = (const float*)d_in[11];
  float* out = (float*)d_out;

  int N = in_sizes[0];
  int E = in_sizes[1] / 2;
  const int* src = edge;
  const int* dst = edge + E;

  int N4 = N * 4;
  int bandsz = (N + NBAND - 1) / NBAND;   // src band size (50000 < 65536)
  int nbuck = (N + (1 << BSHIFT) - 1) >> BSHIFT;   // 25 for N=200000
  int nsub = nbuck * 8;                            // 1024-node subranges
  int cap4 = E / (nbuck * BREP) + 8000;            // per (bucket,rep) region
  int cap2 = E / nsub + 2048;                      // per-subrange region

  float* ws = (float*)d_ws;
  size_t off = 0;
  unsigned short* z2 = (unsigned short*)(ws + off); off += (size_t)N * 16; // N*32 bf16
  float* pooled  = ws + off; off += (size_t)NGRAPH * FEATS;
  float* stats   = ws + off; off += (size_t)NGRAPH * 128;   // double buffer
  float* counts  = ws + off; off += NGRAPH;
  unsigned short* hbf = (unsigned short*)(ws + off); off += (size_t)N * 16; // N*32 ushorts
  unsigned short* whb = (unsigned short*)(ws + off); off += 8192;  // 8*2048 ushorts
  unsigned short* wob = (unsigned short*)(ws + off); off += 8192;
  int* iws = (int*)(ws + off);
  size_t ioff = 0;
  int* degseg   = iws + ioff; ioff += N4;   // [dst][srcband]
  int* rowseg   = iws + ioff; ioff += N4;
  unsigned int* curpk = (unsigned int*)(iws + ioff); ioff += N;  // fallback cursors
  unsigned short* adj = (unsigned short*)(iws + ioff); ioff += (E + 1) / 2; // band-rel ushort
  int* bsum     = iws + ioff; ioff += 4096;
  int* typemask = iws + ioff; ioff += NGRAPH;
  int* bucketcnt = iws + ioff; ioff += BREP * MAXBUCK;
  int* subcnt   = iws + ioff; ioff += nsub;
  unsigned int* ebuf = (unsigned int*)(iws + ioff); ioff += (size_t)nbuck * BREP * cap4;
  unsigned int* ebuf2 = (unsigned int*)(iws + ioff); ioff += (size_t)nsub * cap2;
  bool fastCSR = ((off + ioff) * sizeof(float) <= ws_size) && (nbuck <= MAXBUCK)
               && (bandsz < 65536);

  int eb = (E + 255) / 256;
  int eb8 = (E + 2047) / 2048;              // k_bin: 8 edges/thread
  int nb4 = (N4 + 255) / 256;               // scan over 4N segment counters
  int nb8 = (int)(((size_t)N * 8 + 255) / 256);
  int tiles = (N + 15) / 16;
  int mb = (tiles + 3) / 4;   // conv0: 4 waves (tiles) per block
  int ib = nb4;               // k_init grid covers max(4N, NGRAPH*FEATS)
  if (ib < (NGRAPH * FEATS + 255) / 256) ib = (NGRAPH * FEATS + 255) / 256;

  int dband = (N + NBAND - 1) / NBAND;

  k_init<<<ib, 256, 0, stream>>>(pooled, counts, stats, degseg, typemask, curpk,
                                 bucketcnt, subcnt, Wh, Wo, whb, wob, N4, N, nsub);
  k_embed<<<nb8, 256, 0, stream>>>(x, batch, emb, hbf, typemask, counts, N);
  k_pool0<<<(NGRAPH * 32 + 255) / 256, 256, 0, stream>>>(typemask, emb, pooled);

  if (fastCSR) {
    // two-level bin -> exact hist -> scan -> LDS scatter (all 1x scans)
    k_bin<<<eb8, 256, 0, stream>>>(src, dst, E, cap4, bucketcnt, ebuf, bandsz);
    k_bin2<<<nbuck * BREP, 1024, 0, stream>>>(ebuf, bucketcnt, cap4, subcnt, ebuf2, cap2);
    k_histL2<<<nsub, 1024, 0, stream>>>(ebuf2, subcnt, cap2, degseg, N);
    k_scan_block<<<nb4, 256, 0, stream>>>(degseg, rowseg, bsum, N4);
    k_scan_bsum<<<1, 256, 0, stream>>>(bsum, nb4);
    k_scan_add<<<nb4, 256, 0, stream>>>(rowseg, bsum, N4);
    k_scatL2<<<nsub, 1024, 0, stream>>>(ebuf2, subcnt, cap2, rowseg, curpk, adj, E, N);
  } else {
    // fallback: r12 merged banded hist/scatter
    k_hist<<<NBAND * eb, 256, 0, stream>>>(dst, src, degseg, E, eb, dband, bandsz, N);
    k_scan_block<<<nb4, 256, 0, stream>>>(degseg, rowseg, bsum, N4);
    k_scan_bsum<<<1, 256, 0, stream>>>(bsum, nb4);
    k_scan_add<<<nb4, 256, 0, stream>>>(rowseg, bsum, N4);
    k_scatter<<<NBAND * eb, 256, 0, stream>>>(src, dst, rowseg, curpk, adj, E, eb,
                                              dband, bandsz, N);
  }

  // fully co-resident conv grid: 8 blocks/CU x 256 CUs
  const int GCONV = 2048;

  for (int i = 0; i < 8; i++) {
    float* sCur = stats + (size_t)(i & 1) * NGRAPH * 64;
    float* sOth = stats + (size_t)((i + 1) & 1) * NGRAPH * 64;
    if (i == 0) {
      k_conv0<<<mb, 256, 0, stream>>>(hbf, adj, rowseg, degseg, x, emb,
                                      whb, bh, wob, bo,
                                      batch, z2, sCur, sOth, bandsz, N);
    } else {
      k_conv<<<GCONV, 256, 0, stream>>>(hbf, adj, rowseg, degseg,
                                        whb + (size_t)i * 2048, bh + (size_t)i * 64,
                                        wob + (size_t)i * 2048, bo + (size_t)i * 32,
                                        batch, z2, sCur, sOth, bandsz, N);
    }
    k_norm<<<nb8, 256, 0, stream>>>(hbf, z2, sCur, counts, batch, pooled, i, N);
  }
  k_head<<<NGRAPH, 64, 0, stream>>>(pooled, W_hid, b_hid, W_out, b_out, out);
}

// Round 16
// 761.761 us; speedup vs baseline: 1.0266x; 1.0266x over previous
//
#include <hip/hip_runtime.h>
#include <math.h>

#define NGRAPH 512
#define FEATS 288   // (8+1)*32
#define EPS 1e-5f
#define NBAND 4     // src-band count for L2-resident gather (conv sweep)
#define MAXBUCK 32  // bucket arrays sized for up to 32 (runtime nbuck = 25)
#define BREP 4      // replicated global counters per bucket
#define BSHIFT 13   // bucket node range 8192 = 1<<13
#define SUBR 1024   // nodes per scatter/hist subrange block
#define IMGCAP 20480 // LDS adj image capacity (entries); expected max ~17k

typedef __attribute__((ext_vector_type(8))) short short8v;
typedef __attribute__((ext_vector_type(8))) unsigned short ushort8v;
typedef __attribute__((ext_vector_type(4))) unsigned short ushort4v;
typedef __attribute__((ext_vector_type(4))) float float4v;

// f32 -> bf16 round-to-nearest-even
__device__ __forceinline__ unsigned short f2bf(float f) {
  unsigned int u = __float_as_uint(f);
  u += 0x7fff + ((u >> 16) & 1);
  return (unsigned short)(u >> 16);
}
__device__ __forceinline__ float bf2f(unsigned short u) {
  return __uint_as_float(((unsigned int)u) << 16);
}

// exact src-band: 3 compares (no div)
__device__ __forceinline__ int srcband(int s, int bandsz) {
  return (s >= bandsz) + (s >= 2 * bandsz) + (s >= 3 * bandsz);
}

// order-preserving float atomic max (works for mixed signs, init -inf)
__device__ __forceinline__ void atomicMaxF(float* addr, float v) {
  if (v >= 0.f) atomicMax((int*)addr, __float_as_int(v));
  else atomicMin((unsigned int*)addr, __float_as_uint(v));
}

// zero/init everything once per call; first 8 blocks also convert weights
// to MFMA fragment order (absorbs the old k_prep launch).
__global__ void k_init(float* __restrict__ pooled, float* __restrict__ counts,
                       float* __restrict__ stats, int* __restrict__ degseg,
                       int* __restrict__ typemask, unsigned int* __restrict__ curpk,
                       int* __restrict__ bucketcnt, int* __restrict__ subcnt,
                       const float* __restrict__ Wh, const float* __restrict__ Wo,
                       unsigned short* __restrict__ whb, unsigned short* __restrict__ wob,
                       int N4, int N, int nsub) {
  int i = blockIdx.x * blockDim.x + threadIdx.x;
  if (i < NGRAPH * FEATS) pooled[i] = -INFINITY;
  if (i < NGRAPH) { counts[i] = 0.f; typemask[i] = 0; }
  if (i < NGRAPH * 128) stats[i] = 0.f;       // both buffers
  if (i < N4) degseg[i] = 0;
  if (i < N) curpk[i] = 0u;                   // fallback cursors
  if (i < BREP * MAXBUCK) bucketcnt[i] = 0;
  if (i < nsub) subcnt[i] = 0;

  if (blockIdx.x < 8) {
    int conv = blockIdx.x;
    const float* wh = Wh + (size_t)conv * 2048;
    const float* wo = Wo + (size_t)conv * 2048;
    unsigned short* oh = whb + (size_t)conv * 2048;
    unsigned short* oo = wob + (size_t)conv * 2048;
    for (int p = threadIdx.x; p < 2048; p += blockDim.x) {
      int rem = p & 511, l = rem >> 3, ii = rem & 7;
      int nt = p >> 9;
      int k = (l >> 4) * 8 + ii;
      int n = nt * 16 + (l & 15);
      oh[p] = f2bf(wh[k * 64 + n]);          // Wh is [32][64]
      int blk = p >> 9, nt2 = blk >> 1, ks = blk & 1;
      int k2 = ks * 32 + (l >> 4) * 8 + ii;
      int n2 = nt2 * 16 + (l & 15);
      oo[p] = f2bf(wo[k2 * 32 + n2]);        // Wo is [64][32]
    }
  }
}

// 8 threads/node: thread q writes channels 4q..4q+3 of hbf (bf16 only).
__global__ __launch_bounds__(256) void k_embed(
    const int* __restrict__ x, const int* __restrict__ batch,
    const float* __restrict__ emb, unsigned short* __restrict__ hbf,
    int* __restrict__ typemask, float* __restrict__ counts, int N) {
  long t = (long)blockIdx.x * blockDim.x + threadIdx.x;
  int n = (int)(t >> 3), q = (int)(t & 7);
  int lane = threadIdx.x & 63;
  bool valid = (n < N);
  int g = 0, tt = 0;
  if (valid) {
    g = batch[n];
    tt = x[n];
    float4 e = *((const float4*)(emb + (size_t)tt * 32 + q * 4));
    ushort4v hb;
    hb[0] = f2bf(e.x); hb[1] = f2bf(e.y); hb[2] = f2bf(e.z); hb[3] = f2bf(e.w);
    *((ushort4v*)(hbf + (size_t)n * 32 + q * 4)) = hb;
  }
  int g0 = __shfl(g, 0);
  bool uniform = __all(valid) && __all(g == g0);
  int m = valid ? (1 << tt) : 0;
  if (uniform) {
    #pragma unroll
    for (int d = 1; d < 64; d <<= 1) m |= __shfl_xor(m, d);
    if (lane == 0) {
      atomicOr(&typemask[g0], m);
      atomicAdd(&counts[g0], 8.f);   // 64 lanes = 8 nodes
    }
  } else if (valid && q == 0) {
    atomicOr(&typemask[g], m);
    atomicAdd(&counts[g], 1.f);
  }
}

// pooled[g][0:32] = max over types present in g of emb[t][:]
__global__ void k_pool0(const int* __restrict__ typemask, const float* __restrict__ emb,
                        float* __restrict__ pooled) {
  int i = blockIdx.x * blockDim.x + threadIdx.x;
  if (i >= NGRAPH * 32) return;
  int g = i >> 5, c = i & 31;
  int m = typemask[g];
  float v = -INFINITY;
  #pragma unroll
  for (int t = 0; t < 6; t++)
    if (m & (1 << t)) v = fmaxf(v, emb[t * 32 + c]);
  pooled[(size_t)g * FEATS + c] = v;
}

// ---------------- CSR build v3: two-level bin + LDS assembly ----------
__global__ __launch_bounds__(256) void k_bin(
    const int* __restrict__ src, const int* __restrict__ dst, int E,
    int cap4, int* __restrict__ bucketcnt, unsigned int* __restrict__ ebuf,
    int bandsz) {
  __shared__ int lcnt[MAXBUCK];
  __shared__ int gbase[MAXBUCK];
  for (int i = threadIdx.x; i < MAXBUCK; i += 256) lcnt[i] = 0;
  __syncthreads();
  int e0 = blockIdx.x * 2048 + threadIdx.x;
  int bArr[8], rArr[8];
  unsigned int pArr[8];
  #pragma unroll
  for (int it = 0; it < 8; it++) {
    int e = e0 + it * 256;
    bArr[it] = -1;
    if (e < E) {
      int d = dst[e];
      int s = src[e];
      int b = d >> BSHIFT;
      int sb = srcband(s, bandsz);
      pArr[it] = ((unsigned int)(d & ((1 << BSHIFT) - 1)) << 18)
               | ((unsigned int)sb << 16) | (unsigned int)(s - sb * bandsz);
      rArr[it] = atomicAdd(&lcnt[b], 1);
      bArr[it] = b;
    }
  }
  __syncthreads();
  int rep = blockIdx.x & (BREP - 1);
  if (threadIdx.x < MAXBUCK) {
    int b = threadIdx.x;
    int c = lcnt[b];
    gbase[b] = (c > 0) ? atomicAdd(&bucketcnt[rep * MAXBUCK + b], c) : 0;
  }
  __syncthreads();
  #pragma unroll
  for (int it = 0; it < 8; it++) {
    if (bArr[it] >= 0) {
      int b = bArr[it];
      int pos = gbase[b] + rArr[it];
      if (pos < cap4)
        ebuf[((size_t)b * BREP + rep) * cap4 + pos] = pArr[it];
    }
  }
}

// re-partition (bucket,rep) list into 8 per-subrange lists.
__global__ __launch_bounds__(1024) void k_bin2(
    const unsigned int* __restrict__ ebuf, const int* __restrict__ bucketcnt,
    int cap4, int* __restrict__ subcnt, unsigned int* __restrict__ ebuf2,
    int cap2) {
  __shared__ int lcnt[8];
  __shared__ int gbase[8];
  int p = blockIdx.x >> 2;
  int rep = blockIdx.x & 3;
  int cnt = min(bucketcnt[rep * MAXBUCK + p], cap4);
  const unsigned int* base = ebuf + ((size_t)p * BREP + rep) * cap4;
  for (int c0 = 0; c0 < cnt; c0 += 1024) {
    if (threadIdx.x < 8) lcnt[threadIdx.x] = 0;
    __syncthreads();
    int idx = c0 + threadIdx.x;
    int j = -1, rank = 0;
    unsigned int pk = 0;
    if (idx < cnt) {
      pk = base[idx];
      j = (int)((pk >> 28) & 7u);
      rank = atomicAdd(&lcnt[j], 1);
    }
    __syncthreads();
    if (threadIdx.x < 8) {
      int c = lcnt[threadIdx.x];
      gbase[threadIdx.x] = (c > 0) ? atomicAdd(&subcnt[p * 8 + threadIdx.x], c) : 0;
    }
    __syncthreads();
    if (j >= 0) {
      int pos = gbase[j] + rank;
      if (pos < cap2)
        ebuf2[(size_t)(p * 8 + j) * cap2 + pos] = pk;
    }
    __syncthreads();
  }
}

// exact per-segment counts -> degseg (no global atomics, 1x scan)
__global__ __launch_bounds__(1024) void k_histL2(
    const unsigned int* __restrict__ ebuf2, const int* __restrict__ subcnt,
    int cap2, int* __restrict__ degseg, int N) {
  __shared__ unsigned int cpk[SUBR];
  int s = blockIdx.x;
  int node0 = s << 10;
  if (node0 >= N) return;
  int nEnd = min(node0 + SUBR, N);
  for (int i = threadIdx.x; i < SUBR; i += 1024) cpk[i] = 0u;
  __syncthreads();
  int cnt = min(subcnt[s], cap2);
  const unsigned int* base = ebuf2 + (size_t)s * cap2;
  for (int idx = threadIdx.x; idx < cnt; idx += 1024) {
    unsigned int pk = base[idx];
    int local = (int)((pk >> 18) & 1023u);
    int sb = (int)((pk >> 16) & 3u);
    atomicAdd(&cpk[local], 1u << (sb * 8));
  }
  __syncthreads();
  for (int i = threadIdx.x; i < nEnd - node0; i += 1024) {
    unsigned int v = cpk[i];
    int* dp = degseg + (size_t)(node0 + i) * 4;
    dp[0] = (int)(v & 0xffu);
    dp[1] = (int)((v >> 8) & 0xffu);
    dp[2] = (int)((v >> 16) & 0xffu);
    dp[3] = (int)(v >> 24);
  }
}

// assemble subrange adj image in LDS, stream to global coalesced (1x scan)
__global__ __launch_bounds__(1024) void k_scatL2(
    const unsigned int* __restrict__ ebuf2, const int* __restrict__ subcnt,
    int cap2, const int* __restrict__ rowseg, unsigned int* __restrict__ curpk,
    unsigned short* __restrict__ adj, int E, int N) {
  __shared__ unsigned short img[IMGCAP];
  __shared__ unsigned int cpk[SUBR];
  int s = blockIdx.x;
  int node0 = s << 10;
  if (node0 >= N) return;
  int nEnd = min(node0 + SUBR, N);
  int imgbase = rowseg[(size_t)node0 * 4];
  int imgend = (nEnd < N) ? rowseg[(size_t)nEnd * 4] : E;
  int isz = imgend - imgbase;
  bool lds = (isz <= IMGCAP);
  for (int i = threadIdx.x; i < SUBR; i += 1024) cpk[i] = 0u;
  __syncthreads();
  int cnt = min(subcnt[s], cap2);
  const unsigned int* base = ebuf2 + (size_t)s * cap2;
  for (int idx = threadIdx.x; idx < cnt; idx += 1024) {
    unsigned int pk = base[idx];
    int local = (int)((pk >> 18) & 1023u);
    int sb = (int)((pk >> 16) & 3u);
    int node = node0 + local;
    int seg = node * 4 + sb;
    unsigned short srel = (unsigned short)(pk & 0xffffu);
    if (lds) {
      unsigned int old = atomicAdd(&cpk[local], 1u << (sb * 8));
      int rank = (int)((old >> (sb * 8)) & 0xffu);
      img[rowseg[seg] + rank - imgbase] = srel;
    } else {
      unsigned int old = atomicAdd(&curpk[seg >> 2], 1u << ((seg & 3) * 8));
      int rank = (int)((old >> ((seg & 3) * 8)) & 0xffu);
      adj[rowseg[seg] + rank] = srel;
    }
  }
  __syncthreads();
  if (lds) {
    for (int i = threadIdx.x; i < isz; i += 1024)
      adj[imgbase + i] = img[i];
  }
}

// ---- fallback (r12) hist/scatter, used only if ws too small ----
__global__ void k_hist(const int* __restrict__ dst, const int* __restrict__ src,
                       int* __restrict__ degseg, int E, int eb,
                       int dband, int bandsz, int N) {
  int band = blockIdx.x / eb;
  int e = (blockIdx.x - band * eb) * blockDim.x + threadIdx.x;
  if (e >= E) return;
  int bandlo = band * dband;
  int bandhi = min(bandlo + dband, N);
  int d = dst[e];
  if (d < bandlo || d >= bandhi) return;
  int sb = srcband(src[e], bandsz);
  atomicAdd(&degseg[(size_t)d * 4 + sb], 1);
}

__global__ void k_scatter(const int* __restrict__ src, const int* __restrict__ dst,
                          const int* __restrict__ rowseg, unsigned int* __restrict__ curpk,
                          unsigned short* __restrict__ adj, int E,
                          int eb, int dband, int bandsz, int N) {
  int band = blockIdx.x / eb;
  int e = (blockIdx.x - band * eb) * blockDim.x + threadIdx.x;
  if (e >= E) return;
  int bandlo = band * dband;
  int bandhi = min(bandlo + dband, N);
  int d = dst[e];
  if (d < bandlo || d >= bandhi) return;
  int s = src[e];
  int sb = srcband(s, bandsz);
  int seg = d * 4 + sb;
  unsigned int old = atomicAdd(&curpk[seg >> 2], 1u << ((seg & 3) * 8));
  int local = (int)((old >> ((seg & 3) * 8)) & 0xffu);
  adj[rowseg[seg] + local] = (unsigned short)(s - sb * bandsz);
}

__global__ void k_scan_block(const int* __restrict__ deg, int* __restrict__ excl,
                             int* __restrict__ bsum, int N) {
  __shared__ int s[256];
  int i = blockIdx.x * 256 + threadIdx.x;
  int t = threadIdx.x;
  int v = (i < N) ? deg[i] : 0;
  s[t] = v;
  __syncthreads();
  for (int off = 1; off < 256; off <<= 1) {
    int add = (t >= off) ? s[t - off] : 0;
    __syncthreads();
    s[t] += add;
    __syncthreads();
  }
  if (i < N) excl[i] = s[t] - v;
  if (t == 255) bsum[blockIdx.x] = s[255];
}

__global__ void k_scan_bsum(int* __restrict__ bsum, int nb) {
  __shared__ int s[256];
  __shared__ int carry;
  int t = threadIdx.x;
  if (t == 0) carry = 0;
  __syncthreads();
  for (int base = 0; base < nb; base += 256) {
    int i = base + t;
    int v = (i < nb) ? bsum[i] : 0;
    s[t] = v;
    __syncthreads();
    for (int off = 1; off < 256; off <<= 1) {
      int add = (t >= off) ? s[t - off] : 0;
      __syncthreads();
      s[t] += add;
      __syncthreads();
    }
    if (i < nb) bsum[i] = s[t] - v + carry;
    __syncthreads();
    if (t == 0) carry += s[255];
    __syncthreads();
  }
}

__global__ void k_scan_add(int* __restrict__ excl, const int* __restrict__ bsum, int N) {
  int i = blockIdx.x * 256 + threadIdx.x;
  if (i < N) excl[i] = excl[i] + bsum[blockIdx.x];
}

// ---------------- fused conv: phase-aligned band sweep + quarter-row gather --
// r14 config VERBATIM (measured best: 56.5us, FETCH 115MB): FULLY CO-RESIDENT
// GRID of 2048 blocks (8/CU), __launch_bounds__(256,8), T=2 tiles/wave at
// stride 8192, BAND OUTER tile inner (each XCD's L2 holds only the band's
// hbf slice ~2.8MB). Quarter-row gather, no butterfly. adj entries are
// band-relative ushorts: src = b*bandsz + entry.
// r15 lesson: balanced contiguous tile assignment was NULL-to-negative —
// the 2-vs-1-tile skew is absorbed by the 8-blocks/CU wave interleave; conv
// is at its algorithmic byte floor at the random-access fabric throughput.
__global__ __launch_bounds__(256, 8) void k_conv(
    const unsigned short* __restrict__ hbf,
    const unsigned short* __restrict__ adj, const int* __restrict__ rowseg,
    const int* __restrict__ degseg,
    const unsigned short* __restrict__ whb, const float* __restrict__ bh,
    const unsigned short* __restrict__ wob, const float* __restrict__ bo,
    const int* __restrict__ batch, unsigned short* __restrict__ z2,
    float* __restrict__ stats, float* __restrict__ statsOther,
    int bandsz, int N) {
  __shared__ unsigned short sWhB[4 * 64 * 8];     // [nt][lane][i]
  __shared__ unsigned short sWoB[2 * 2 * 64 * 8]; // [nt2*2+ks][lane][i]
  __shared__ unsigned short st[4][16][72];        // per-wave t buf, +8 pad

  {
    int zi = blockIdx.x * 256 + threadIdx.x;
    if (zi < NGRAPH * 64) statsOther[zi] = 0.f;
    int p = threadIdx.x * 8;
    *((ushort8v*)&sWhB[p]) = *((const ushort8v*)&whb[p]);
    *((ushort8v*)&sWoB[p]) = *((const ushort8v*)&wob[p]);
  }
  __syncthreads();

  int wid = threadIdx.x >> 6;
  int lane = threadIdx.x & 63;
  int col = lane & 15;
  int grp = lane >> 4;
  int gwave = blockIdx.x * 4 + wid;        // 0..8191
  int wstride = gridDim.x * 4;             // 8192
  int ntiles = (N + 15) >> 4;

  const unsigned short* __restrict__ qb = hbf + grp * 8;

  float keepT[2][8];
  #pragma unroll
  for (int t = 0; t < 2; t++)
    #pragma unroll
    for (int i = 0; i < 8; i++) keepT[t][i] = 0.f;

  // band-major gather sweep
  #pragma unroll
  for (int b = 0; b < 4; b++) {
    const unsigned short* __restrict__ bq = qb + (size_t)(b * bandsz) * 32;
    #pragma unroll
    for (int t = 0; t < 2; t++) {
      int tile = gwave + t * wstride;
      if (tile >= ntiles) continue;        // wave-uniform branch
      int node = tile * 16 + col;
      int s0 = 0, dg = 0;
      if (node < N) {
        s0 = rowseg[(size_t)node * 4 + b];
        dg = degseg[(size_t)node * 4 + b];
      }
      int k = 0;
      for (; k + 4 <= dg; k += 4) {
        int sA = adj[s0 + k + 0];
        int sB = adj[s0 + k + 1];
        int sC = adj[s0 + k + 2];
        int sD = adj[s0 + k + 3];
        ushort8v a = *((const ushort8v*)(bq + (size_t)sA * 32));
        ushort8v bv = *((const ushort8v*)(bq + (size_t)sB * 32));
        ushort8v c = *((const ushort8v*)(bq + (size_t)sC * 32));
        ushort8v d = *((const ushort8v*)(bq + (size_t)sD * 32));
        #pragma unroll
        for (int i = 0; i < 8; i++) {
          keepT[t][i] += bf2f(a[i]);
          keepT[t][i] += bf2f(bv[i]);
          keepT[t][i] += bf2f(c[i]);
          keepT[t][i] += bf2f(d[i]);
        }
      }
      if (k + 2 <= dg) {
        int sA = adj[s0 + k + 0];
        int sB = adj[s0 + k + 1];
        ushort8v a = *((const ushort8v*)(bq + (size_t)sA * 32));
        ushort8v bv = *((const ushort8v*)(bq + (size_t)sB * 32));
        #pragma unroll
        for (int i = 0; i < 8; i++) {
          keepT[t][i] += bf2f(a[i]);
          keepT[t][i] += bf2f(bv[i]);
        }
        k += 2;
      }
      if (k < dg) {
        int sA = adj[s0 + k];
        ushort8v a = *((const ushort8v*)(bq + (size_t)sA * 32));
        #pragma unroll
        for (int i = 0; i < 8; i++) keepT[t][i] += bf2f(a[i]);
      }
    }
  }

  // epilogue per tile: z -> MLP -> z2, stats
  #pragma unroll
  for (int t = 0; t < 2; t++) {
    int tile = gwave + t * wstride;
    if (tile >= ntiles) continue;
    int base = tile * 16;
    int node = base + col;

    float zf[8];
    if (node < N) {
      ushort8v own = *((const ushort8v*)(hbf + (size_t)node * 32 + grp * 8));
      #pragma unroll
      for (int i = 0; i < 8; i++) zf[i] = bf2f(own[i]) + keepT[t][i];
    } else {
      #pragma unroll
      for (int i = 0; i < 8; i++) zf[i] = 0.f;
    }
    short8v afrag;
    #pragma unroll
    for (int i = 0; i < 8; i++) afrag[i] = (short)f2bf(zf[i]);

    // layer 1: t1 = relu(z @ Wh + bh) -> bf16 in per-wave LDS
    #pragma unroll
    for (int nt = 0; nt < 4; nt++) {
      float b = bh[nt * 16 + col];
      float4v acc1 = {b, b, b, b};
      short8v bfrag = *((const short8v*)&sWhB[(nt * 64 + lane) * 8]);
      acc1 = __builtin_amdgcn_mfma_f32_16x16x32_bf16(afrag, bfrag, acc1, 0, 0, 0);
      #pragma unroll
      for (int r = 0; r < 4; r++) {
        st[wid][grp * 4 + r][nt * 16 + col] = f2bf(fmaxf(acc1[r], 0.f));
      }
    }
    // same-wave LDS RAW/WAR: DS ops are in-order per wave.

    // layer 2: o = t1 @ Wo + bo
    short8v a2[2];
    #pragma unroll
    for (int ks = 0; ks < 2; ks++)
      a2[ks] = *((const short8v*)&st[wid][col][ks * 32 + grp * 8]);

    float4v acc2[2];
    #pragma unroll
    for (int nt2 = 0; nt2 < 2; nt2++) {
      float b = bo[nt2 * 16 + col];
      acc2[nt2] = (float4v){b, b, b, b};
      #pragma unroll
      for (int ks = 0; ks < 2; ks++) {
        short8v bfrag = *((const short8v*)&sWoB[((nt2 * 2 + ks) * 64 + lane) * 8]);
        acc2[nt2] = __builtin_amdgcn_mfma_f32_16x16x32_bf16(a2[ks], bfrag, acc2[nt2], 0, 0, 0);
      }
    }

    // store z2 (bf16, nt streaming store)
    #pragma unroll
    for (int nt2 = 0; nt2 < 2; nt2++) {
      #pragma unroll
      for (int r = 0; r < 4; r++) {
        int nd = base + grp * 4 + r;
        if (nd < N)
          __builtin_nontemporal_store(f2bf(acc2[nt2][r]), z2 + (size_t)nd * 32 + nt2 * 16 + col);
      }
    }

    // per-graph stats
    int g0 = batch[base];
    int gLast = batch[min(base + 15, N - 1)];
    if ((base + 16 <= N) && g0 == gLast) {
      #pragma unroll
      for (int nt2 = 0; nt2 < 2; nt2++) {
        float s = acc2[nt2][0] + acc2[nt2][1] + acc2[nt2][2] + acc2[nt2][3];
        float ss = acc2[nt2][0] * acc2[nt2][0] + acc2[nt2][1] * acc2[nt2][1]
                 + acc2[nt2][2] * acc2[nt2][2] + acc2[nt2][3] * acc2[nt2][3];
        s += __shfl_xor(s, 16); s += __shfl_xor(s, 32);
        ss += __shfl_xor(ss, 16); ss += __shfl_xor(ss, 32);
        if (grp == 0) {
          atomicAdd(&stats[(size_t)g0 * 64 + nt2 * 16 + col], s);
          atomicAdd(&stats[(size_t)g0 * 64 + 32 + nt2 * 16 + col], ss);
        }
      }
    } else {
      #pragma unroll
      for (int nt2 = 0; nt2 < 2; nt2++) {
        #pragma unroll
        for (int r = 0; r < 4; r++) {
          int nd = base + grp * 4 + r;
          if (nd < N) {
            int g = batch[nd];
            float v = acc2[nt2][r];
            atomicAdd(&stats[(size_t)g * 64 + nt2 * 16 + col], v);
            atomicAdd(&stats[(size_t)g * 64 + 32 + nt2 * 16 + col], v * v);
          }
        }
      }
    }
  }
}

// ---------------- conv 0 specialization ----------------
__global__ __launch_bounds__(256, 4) void k_conv0(
    const unsigned short* __restrict__ hbf,
    const unsigned short* __restrict__ adj, const int* __restrict__ rowseg,
    const int* __restrict__ degseg,
    const int* __restrict__ x, const float* __restrict__ emb,
    const unsigned short* __restrict__ whb, const float* __restrict__ bh,
    const unsigned short* __restrict__ wob, const float* __restrict__ bo,
    const int* __restrict__ batch, unsigned short* __restrict__ z2,
    float* __restrict__ stats, float* __restrict__ statsOther,
    int bandsz, int N) {
  __shared__ unsigned short sWhB[4 * 64 * 8];
  __shared__ unsigned short sWoB[2 * 2 * 64 * 8];
  __shared__ unsigned short st[4][16][72];
  __shared__ float sEmb[6][32];

  {
    int zi = blockIdx.x * 256 + threadIdx.x;
    if (zi < NGRAPH * 64) statsOther[zi] = 0.f;
    int p = threadIdx.x * 8;
    *((ushort8v*)&sWhB[p]) = *((const ushort8v*)&whb[p]);
    *((ushort8v*)&sWoB[p]) = *((const ushort8v*)&wob[p]);
    if (threadIdx.x < 192) ((float*)sEmb)[threadIdx.x] = emb[threadIdx.x];
  }
  __syncthreads();

  int wid = threadIdx.x >> 6;
  int lane = threadIdx.x & 63;
  int tile = blockIdx.x * 4 + wid;
  int base = tile * 16;
  if (base >= N) return;
  int col = lane & 15;
  int grp = lane >> 4;
  int node = base + col;

  int sArr[4] = {0, 0, 0, 0}, dArr[4] = {0, 0, 0, 0};
  if (node < N) {
    int4 s4 = *((const int4*)(rowseg + (size_t)node * 4));
    int4 d4 = *((const int4*)(degseg + (size_t)node * 4));
    sArr[0] = s4.x; sArr[1] = s4.y; sArr[2] = s4.z; sArr[3] = s4.w;
    dArr[0] = d4.x; dArr[1] = d4.y; dArr[2] = d4.z; dArr[3] = d4.w;
  }

  float c0 = 0.f, c1 = 0.f, c2 = 0.f, c3 = 0.f, c4 = 0.f, c5 = 0.f;
  #pragma unroll
  for (int b = 0; b < 4; b++) {
    int s0 = sArr[b], dg = dArr[b];
    int bbase = b * bandsz;
    for (int j = grp; j < dg; j += 4) {
      int sA = bbase + (int)adj[s0 + j];
      int tA = x[sA];
      c0 += (tA == 0) ? 1.f : 0.f; c1 += (tA == 1) ? 1.f : 0.f;
      c2 += (tA == 2) ? 1.f : 0.f; c3 += (tA == 3) ? 1.f : 0.f;
      c4 += (tA == 4) ? 1.f : 0.f; c5 += (tA == 5) ? 1.f : 0.f;
    }
  }

  c0 += __shfl_xor(c0, 16); c0 += __shfl_xor(c0, 32);
  c1 += __shfl_xor(c1, 16); c1 += __shfl_xor(c1, 32);
  c2 += __shfl_xor(c2, 16); c2 += __shfl_xor(c2, 32);
  c3 += __shfl_xor(c3, 16); c3 += __shfl_xor(c3, 32);
  c4 += __shfl_xor(c4, 16); c4 += __shfl_xor(c4, 32);
  c5 += __shfl_xor(c5, 16); c5 += __shfl_xor(c5, 32);

  float zf[8];
  if (node < N) {
    ushort8v own = *((const ushort8v*)(hbf + (size_t)node * 32 + grp * 8));
    #pragma unroll
    for (int i = 0; i < 8; i++) {
      int ch = grp * 8 + i;
      float v = bf2f(own[i]);
      v = fmaf(c0, sEmb[0][ch], v);
      v = fmaf(c1, sEmb[1][ch], v);
      v = fmaf(c2, sEmb[2][ch], v);
      v = fmaf(c3, sEmb[3][ch], v);
      v = fmaf(c4, sEmb[4][ch], v);
      v = fmaf(c5, sEmb[5][ch], v);
      zf[i] = v;
    }
  } else {
    #pragma unroll
    for (int i = 0; i < 8; i++) zf[i] = 0.f;
  }
  short8v afrag;
  #pragma unroll
  for (int i = 0; i < 8; i++) afrag[i] = (short)f2bf(zf[i]);

  #pragma unroll
  for (int nt = 0; nt < 4; nt++) {
    float b = bh[nt * 16 + col];
    float4v acc1 = {b, b, b, b};
    short8v bfrag = *((const short8v*)&sWhB[(nt * 64 + lane) * 8]);
    acc1 = __builtin_amdgcn_mfma_f32_16x16x32_bf16(afrag, bfrag, acc1, 0, 0, 0);
    #pragma unroll
    for (int r = 0; r < 4; r++) {
      st[wid][grp * 4 + r][nt * 16 + col] = f2bf(fmaxf(acc1[r], 0.f));
    }
  }

  short8v a2[2];
  #pragma unroll
  for (int ks = 0; ks < 2; ks++)
    a2[ks] = *((const short8v*)&st[wid][col][ks * 32 + grp * 8]);

  float4v acc2[2];
  #pragma unroll
  for (int nt2 = 0; nt2 < 2; nt2++) {
    float b = bo[nt2 * 16 + col];
    acc2[nt2] = (float4v){b, b, b, b};
    #pragma unroll
    for (int ks = 0; ks < 2; ks++) {
      short8v bfrag = *((const short8v*)&sWoB[((nt2 * 2 + ks) * 64 + lane) * 8]);
      acc2[nt2] = __builtin_amdgcn_mfma_f32_16x16x32_bf16(a2[ks], bfrag, acc2[nt2], 0, 0, 0);
    }
  }

  #pragma unroll
  for (int nt2 = 0; nt2 < 2; nt2++) {
    #pragma unroll
    for (int r = 0; r < 4; r++) {
      int nd = base + grp * 4 + r;
      if (nd < N)
        __builtin_nontemporal_store(f2bf(acc2[nt2][r]), z2 + (size_t)nd * 32 + nt2 * 16 + col);
    }
  }

  int g0 = batch[base];
  int gLast = batch[min(base + 15, N - 1)];
  if ((base + 16 <= N) && g0 == gLast) {
    #pragma unroll
    for (int nt2 = 0; nt2 < 2; nt2++) {
      float s = acc2[nt2][0] + acc2[nt2][1] + acc2[nt2][2] + acc2[nt2][3];
      float ss = acc2[nt2][0] * acc2[nt2][0] + acc2[nt2][1] * acc2[nt2][1]
               + acc2[nt2][2] * acc2[nt2][2] + acc2[nt2][3] * acc2[nt2][3];
      s += __shfl_xor(s, 16); s += __shfl_xor(s, 32);
      ss += __shfl_xor(ss, 16); ss += __shfl_xor(ss, 32);
      if (grp == 0) {
        atomicAdd(&stats[(size_t)g0 * 64 + nt2 * 16 + col], s);
        atomicAdd(&stats[(size_t)g0 * 64 + 32 + nt2 * 16 + col], ss);
      }
    }
  } else {
    #pragma unroll
    for (int nt2 = 0; nt2 < 2; nt2++) {
      #pragma unroll
      for (int r = 0; r < 4; r++) {
        int nd = base + grp * 4 + r;
        if (nd < N) {
          int g = batch[nd];
          float v = acc2[nt2][r];
          atomicAdd(&stats[(size_t)g * 64 + nt2 * 16 + col], v);
          atomicAdd(&stats[(size_t)g * 64 + 32 + nt2 * 16 + col], v * v);
        }
      }
    }
  }
}

// h = relu(h + (z2-mean)*inv) with h kept in bf16 (hbf). 8 threads/node.
__global__ __launch_bounds__(256) void k_norm(
    unsigned short* __restrict__ hbf, const unsigned short* __restrict__ z2,
    const float* __restrict__ stats, const float* __restrict__ counts,
    const int* __restrict__ batch, float* __restrict__ pooled, int conv, int N) {
  long t = (long)blockIdx.x * blockDim.x + threadIdx.x;
  int n = (int)(t >> 3), q = (int)(t & 7);
  int lane = threadIdx.x & 63;
  bool valid = (n < N);

  int g = 0;
  float r0 = -INFINITY, r1 = -INFINITY, r2 = -INFINITY, r3 = -INFINITY;
  if (valid) {
    g = batch[n];
    float cnt = counts[g];
    float4 sv = *((const float4*)(stats + (size_t)g * 64 + q * 4));
    float4 qv = *((const float4*)(stats + (size_t)g * 64 + 32 + q * 4));
    float m0 = 0.f, m1 = 0.f, m2 = 0.f, m3 = 0.f;
    float i0 = 0.f, i1 = 0.f, i2 = 0.f, i3 = 0.f;
    if (cnt > 0.f) {
      m0 = sv.x / cnt; m1 = sv.y / cnt; m2 = sv.z / cnt; m3 = sv.w / cnt;
      i0 = rsqrtf(fmaxf(qv.x / cnt - m0 * m0, 0.f) + EPS);
      i1 = rsqrtf(fmaxf(qv.y / cnt - m1 * m1, 0.f) + EPS);
      i2 = rsqrtf(fmaxf(qv.z / cnt - m2 * m2, 0.f) + EPS);
      i3 = rsqrtf(fmaxf(qv.w / cnt - m3 * m3, 0.f) + EPS);
    }
    ushort4v hb = *((const ushort4v*)(hbf + (size_t)n * 32 + q * 4));
    ushort4v zv = *((const ushort4v*)(z2 + (size_t)n * 32 + q * 4));
    r0 = fmaxf(bf2f(hb[0]) + (bf2f(zv[0]) - m0) * i0, 0.f);
    r1 = fmaxf(bf2f(hb[1]) + (bf2f(zv[1]) - m1) * i1, 0.f);
    r2 = fmaxf(bf2f(hb[2]) + (bf2f(zv[2]) - m2) * i2, 0.f);
    r3 = fmaxf(bf2f(hb[3]) + (bf2f(zv[3]) - m3) * i3, 0.f);
    hb[0] = f2bf(r0); hb[1] = f2bf(r1); hb[2] = f2bf(r2); hb[3] = f2bf(r3);
    *((ushort4v*)(hbf + (size_t)n * 32 + q * 4)) = hb;
  }

  int g0 = __shfl(g, 0);
  bool uniform = __all(valid) && __all(g == g0);
  if (uniform) {
    float m0 = r0, m1 = r1, m2 = r2, m3 = r3;
    #pragma unroll
    for (int d = 8; d < 64; d <<= 1) {
      m0 = fmaxf(m0, __shfl_xor(m0, d));
      m1 = fmaxf(m1, __shfl_xor(m1, d));
      m2 = fmaxf(m2, __shfl_xor(m2, d));
      m3 = fmaxf(m3, __shfl_xor(m3, d));
    }
    if (lane < 8) {
      float* poolrow = pooled + (size_t)g0 * FEATS + (conv + 1) * 32 + lane * 4;
      atomicMaxF(poolrow + 0, m0);
      atomicMaxF(poolrow + 1, m1);
      atomicMaxF(poolrow + 2, m2);
      atomicMaxF(poolrow + 3, m3);
    }
  } else if (valid) {
    float* poolrow = pooled + (size_t)g * FEATS + (conv + 1) * 32 + q * 4;
    atomicMaxF(poolrow + 0, r0);
    atomicMaxF(poolrow + 1, r1);
    atomicMaxF(poolrow + 2, r2);
    atomicMaxF(poolrow + 3, r3);
  }
}

// hid = relu(pooled @ W_hid + b_hid); out = hid @ W_out + b_out
__global__ __launch_bounds__(64) void k_head(
    const float* __restrict__ pooled, const float* __restrict__ W_hid,
    const float* __restrict__ b_hid, const float* __restrict__ W_out,
    const float* __restrict__ b_out, float* __restrict__ out) {
  __shared__ float sp[FEATS];
  __shared__ float sh[64];
  int g = blockIdx.x;
  for (int i = threadIdx.x; i < FEATS; i += 64) sp[i] = pooled[(size_t)g * FEATS + i];
  __syncthreads();
  int j = threadIdx.x;
  float acc = b_hid[j];
  for (int k = 0; k < FEATS; k++) acc = fmaf(sp[k], W_hid[k * 64 + j], acc);
  sh[j] = fmaxf(acc, 0.f);
  __syncthreads();
  if (j < 32) {
    float o = b_out[j];
    #pragma unroll
    for (int k = 0; k < 64; k++) o = fmaf(sh[k], W_out[k * 32 + j], o);
    out[(size_t)g * 32 + j] = o;
  }
}

extern "C" void kernel_launch(void* const* d_in, const int* in_sizes, int n_in,
                              void* d_out, int out_size, void* d_ws, size_t ws_size,
                              hipStream_t stream) {
  const int* x      = (const int*)d_in[0];
  const int* edge   = (const int*)d_in[1];
  const int* batch  = (const int*)d_in[2];
  const float* emb  = (const float*)d_in[3];
  const float* Wh   = (const float*)d_in[4];
  const float* bh   = (const float*)d_in[5];
  const float* Wo   = (const float*)d_in[6];
  const float* bo   = (const float*)d_in[7];
  const float* W_hid = (const float*)d_in[8];
  const float* b_hid = (const float*)d_in[9];
  const float* W_out = (const float*)d_in[10];
  const float* b_out = (const float*)d_in[11];
  float* out = (float*)d_out;

  int N = in_sizes[0];
  int E = in_sizes[1] / 2;
  const int* src = edge;
  const int* dst = edge + E;

  int N4 = N * 4;
  int bandsz = (N + NBAND - 1) / NBAND;   // src band size (50000 < 65536)
  int nbuck = (N + (1 << BSHIFT) - 1) >> BSHIFT;   // 25 for N=200000
  int nsub = nbuck * 8;                            // 1024-node subranges
  int cap4 = E / (nbuck * BREP) + 8000;            // per (bucket,rep) region
  int cap2 = E / nsub + 2048;                      // per-subrange region

  float* ws = (float*)d_ws;
  size_t off = 0;
  unsigned short* z2 = (unsigned short*)(ws + off); off += (size_t)N * 16; // N*32 bf16
  float* pooled  = ws + off; off += (size_t)NGRAPH * FEATS;
  float* stats   = ws + off; off += (size_t)NGRAPH * 128;   // double buffer
  float* counts  = ws + off; off += NGRAPH;
  unsigned short* hbf = (unsigned short*)(ws + off); off += (size_t)N * 16; // N*32 ushorts
  unsigned short* whb = (unsigned short*)(ws + off); off += 8192;  // 8*2048 ushorts
  unsigned short* wob = (unsigned short*)(ws + off); off += 8192;
  int* iws = (int*)(ws + off);
  size_t ioff = 0;
  int* degseg   = iws + ioff; ioff += N4;   // [dst][srcband]
  int* rowseg   = iws + ioff; ioff += N4;
  unsigned int* curpk = (unsigned int*)(iws + ioff); ioff += N;  // fallback cursors
  unsigned short* adj = (unsigned short*)(iws + ioff); ioff += (E + 1) / 2; // band-rel ushort
  int* bsum     = iws + ioff; ioff += 4096;
  int* typemask = iws + ioff; ioff += NGRAPH;
  int* bucketcnt = iws + ioff; ioff += BREP * MAXBUCK;
  int* subcnt   = iws + ioff; ioff += nsub;
  unsigned int* ebuf = (unsigned int*)(iws + ioff); ioff += (size_t)nbuck * BREP * cap4;
  unsigned int* ebuf2 = (unsigned int*)(iws + ioff); ioff += (size_t)nsub * cap2;
  bool fastCSR = ((off + ioff) * sizeof(float) <= ws_size) && (nbuck <= MAXBUCK)
               && (bandsz < 65536);

  int eb = (E + 255) / 256;
  int eb8 = (E + 2047) / 2048;              // k_bin: 8 edges/thread
  int nb4 = (N4 + 255) / 256;               // scan over 4N segment counters
  int nb8 = (int)(((size_t)N * 8 + 255) / 256);
  int tiles = (N + 15) / 16;
  int mb = (tiles + 3) / 4;   // conv0: 4 waves (tiles) per block
  int ib = nb4;               // k_init grid covers max(4N, NGRAPH*FEATS)
  if (ib < (NGRAPH * FEATS + 255) / 256) ib = (NGRAPH * FEATS + 255) / 256;

  int dband = (N + NBAND - 1) / NBAND;

  k_init<<<ib, 256, 0, stream>>>(pooled, counts, stats, degseg, typemask, curpk,
                                 bucketcnt, subcnt, Wh, Wo, whb, wob, N4, N, nsub);
  k_embed<<<nb8, 256, 0, stream>>>(x, batch, emb, hbf, typemask, counts, N);
  k_pool0<<<(NGRAPH * 32 + 255) / 256, 256, 0, stream>>>(typemask, emb, pooled);

  if (fastCSR) {
    // two-level bin -> exact hist -> scan -> LDS scatter (all 1x scans)
    k_bin<<<eb8, 256, 0, stream>>>(src, dst, E, cap4, bucketcnt, ebuf, bandsz);
    k_bin2<<<nbuck * BREP, 1024, 0, stream>>>(ebuf, bucketcnt, cap4, subcnt, ebuf2, cap2);
    k_histL2<<<nsub, 1024, 0, stream>>>(ebuf2, subcnt, cap2, degseg, N);
    k_scan_block<<<nb4, 256, 0, stream>>>(degseg, rowseg, bsum, N4);
    k_scan_bsum<<<1, 256, 0, stream>>>(bsum, nb4);
    k_scan_add<<<nb4, 256, 0, stream>>>(rowseg, bsum, N4);
    k_scatL2<<<nsub, 1024, 0, stream>>>(ebuf2, subcnt, cap2, rowseg, curpk, adj, E, N);
  } else {
    // fallback: r12 merged banded hist/scatter
    k_hist<<<NBAND * eb, 256, 0, stream>>>(dst, src, degseg, E, eb, dband, bandsz, N);
    k_scan_block<<<nb4, 256, 0, stream>>>(degseg, rowseg, bsum, N4);
    k_scan_bsum<<<1, 256, 0, stream>>>(bsum, nb4);
    k_scan_add<<<nb4, 256, 0, stream>>>(rowseg, bsum, N4);
    k_scatter<<<NBAND * eb, 256, 0, stream>>>(src, dst, rowseg, curpk, adj, E, eb,
                                              dband, bandsz, N);
  }

  // fully co-resident conv grid: 8 blocks/CU x 256 CUs
  const int GCONV = 2048;

  for (int i = 0; i < 8; i++) {
    float* sCur = stats + (size_t)(i & 1) * NGRAPH * 64;
    float* sOth = stats + (size_t)((i + 1) & 1) * NGRAPH * 64;
    if (i == 0) {
      k_conv0<<<mb, 256, 0, stream>>>(hbf, adj, rowseg, degseg, x, emb,
                                      whb, bh, wob, bo,
                                      batch, z2, sCur, sOth, bandsz, N);
    } else {
      k_conv<<<GCONV, 256, 0, stream>>>(hbf, adj, rowseg, degseg,
                                        whb + (size_t)i * 2048, bh + (size_t)i * 64,
                                        wob + (size_t)i * 2048, bo + (size_t)i * 32,
                                        batch, z2, sCur, sOth, bandsz, N);
    }
    k_norm<<<nb8, 256, 0, stream>>>(hbf, z2, sCur, counts, batch, pooled, i, N);
  }
  k_head<<<NGRAPH, 64, 0, stream>>>(pooled, W_hid, b_hid, W_out, b_out, out);
}